// Round 14
// baseline (510.015 us; speedup 1.0000x reference)
//
#include <hip/hip_runtime.h>
#include <hip/hip_bf16.h>
#include <stdint.h>

#define B_ 2
#define S_ 2048
#define D_ 2048
#define H_ 32
#define G_ 8
#define HD_ 64
#define KVD (G_*HD_)   // 512

typedef unsigned short u16;
typedef unsigned int u32;
typedef __attribute__((ext_vector_type(8))) short s8v;
typedef __attribute__((ext_vector_type(4))) float f4v;
typedef __attribute__((ext_vector_type(4))) unsigned int u4v;

static __device__ __forceinline__ float bf2f(u16 u){ return __uint_as_float(((u32)u)<<16); }
static __device__ __forceinline__ u16 f2bf(float f){
  u32 b = __float_as_uint(f);
  return (u16)((b + 0x7FFFu + ((b>>16)&1u)) >> 16);
}
static __device__ __forceinline__ u32 pk2bf(float a, float b){
  float2 f2 = make_float2(a, b);
  __hip_bfloat162 h = __float22bfloat162_rn(f2);
  return *(u32*)&h;
}

// ---- fused fp32 -> bf16 convert: x, Wq|Wk|Wv (concatenated 3072x2048), Wo ----
struct CvtArgs {
  const float *x, *wq, *wk, *wv, *wo;
  u16 *xb, *wqkvb, *wob;
};
__global__ void k_cvt5(CvtArgs a){
  const int E0 = 2097152;            // x  (2097152 f4)
  const int E1 = E0 + 1048576;       // Wq
  const int E2 = E1 + 262144;        // Wk
  const int E3 = E2 + 262144;        // Wv
  const int E4 = E3 + 1048576;       // Wo
  int u = blockIdx.x*blockDim.x + threadIdx.x;
  int stride = gridDim.x*blockDim.x;
  for (; u < E4; u += stride){
    const float* s; u16* d; int off;
    if      (u < E0){ s = a.x;  d = a.xb;               off = u; }
    else if (u < E1){ s = a.wq; d = a.wqkvb;            off = u - E0; }
    else if (u < E2){ s = a.wk; d = a.wqkvb + 4194304;  off = u - E1; }
    else if (u < E3){ s = a.wv; d = a.wqkvb + 5242880;  off = u - E2; }
    else            { s = a.wo; d = a.wob;              off = u - E3; }
    float4 f = *(const float4*)(s + (long)off*4);
    uint2 o;
    o.x = (u32)f2bf(f.x) | ((u32)f2bf(f.y)<<16);
    o.y = (u32)f2bf(f.z) | ((u32)f2bf(f.w)<<16);
    *(uint2*)(d + (long)off*4) = o;
  }
}

// ---------------- GEMM: C[m][n] = sum_k A[m][k] * W[n][k], K=2048 ----------------
// 8 waves per 128x128 tile (wave owns 32x64); double-buffered staging.
// MODE 0: f32 store (O-proj) into C.
// MODE 3: QKV-fused epilogue by col-range: [0,2048) rope*C1 -> C(qb, stride 2048);
//         [2048,2560) rope -> C2(kb, stride 512); [2560,3072) transpose -> C3(vtb).
// Q is pre-scaled by C1 = 0.125*log2(e) so fattn's softmax is exp2(s) directly.
template<int MODE>
__global__ __launch_bounds__(512) void k_gemm(const u16* __restrict__ A,
    const u16* __restrict__ Bw,
    void* __restrict__ C, void* __restrict__ C2, void* __restrict__ C3,
    const float* __restrict__ cs, const float* __restrict__ sn,
    int N_unused, int K){
  __shared__ u16 As[2][128*32];
  __shared__ u16 Bs[2][128*32];
  const int tid = threadIdx.x;
  const int lane = tid & 63, wid = tid >> 6;
  const int l15 = lane & 15, l4 = lane >> 4;
  const int wr = wid >> 1, wc = wid & 1;     // 4x2 wave grid; wave tile 32x64
  const long Arow0 = (long)blockIdx.x * 128;
  const long Brow0 = (long)blockIdx.y * 128;
  const int NKS = K >> 5;

  const int sc = tid;
  const int srow = sc >> 2, slot = sc & 3;
  const int ko = slot ^ (srow & 3);
  const u16* srcA0 = A  + (Arow0 + srow)*K + ko*8;
  const u16* srcB0 = Bw + (Brow0 + srow)*K + ko*8;
  auto stage = [&](int ks){
    int bsel = ks & 1, k0 = ks << 5;
    __builtin_amdgcn_global_load_lds(
        (__attribute__((address_space(1))) void*)(void*)(srcA0 + k0),
        (__attribute__((address_space(3))) void*)(&As[bsel][wid*512]), 16, 0, 0);
    __builtin_amdgcn_global_load_lds(
        (__attribute__((address_space(1))) void*)(void*)(srcB0 + k0),
        (__attribute__((address_space(3))) void*)(&Bs[bsel][wid*512]), 16, 0, 0);
  };

  f4v acc[2][4] = {};
  stage(0);
  for (int ks = 0; ks < NKS; ++ks){
    __syncthreads();                 // drains loads staged one iteration ago
    if (ks + 1 < NKS) stage(ks + 1);
    const u16* AsB = As[ks & 1];
    const u16* BsB = Bs[ks & 1];
    s8v af[2], bf[4];
    #pragma unroll
    for (int m = 0; m < 2; ++m){
      int row = wr*32 + m*16 + l15;
      af[m] = *(const s8v*)((const char*)AsB + row*64 + ((l4 ^ (row & 3))<<4));
    }
    #pragma unroll
    for (int n = 0; n < 4; ++n){
      int col = wc*64 + n*16 + l15;
      bf[n] = *(const s8v*)((const char*)BsB + col*64 + ((l4 ^ (col & 3))<<4));
    }
    __builtin_amdgcn_s_setprio(1);
    #pragma unroll
    for (int m = 0; m < 2; ++m)
      #pragma unroll
      for (int n = 0; n < 4; ++n)
        acc[m][n] = __builtin_amdgcn_mfma_f32_16x16x32_bf16(af[m], bf[n], acc[m][n], 0, 0, 0);
    __builtin_amdgcn_s_setprio(0);
  }

  if (MODE == 0){
    #pragma unroll
    for (int m = 0; m < 2; ++m)
      #pragma unroll
      for (int n = 0; n < 4; ++n)
        #pragma unroll
        for (int i = 0; i < 4; ++i){
          long r = Arow0 + wr*32 + m*16 + l4*4 + i;
          long c = Brow0 + wc*64 + n*16 + l15;
          ((float*)C)[r*2048 + c] = acc[m][n][i];
        }
  } else {
    const long col0 = Brow0 + wc*64;   // 64-aligned; wave's region in one segment
    if (col0 < 2560){
      u16* out; long cbase; int stride; float qs;
      if (col0 < 2048){ out = (u16*)C;  cbase = col0;        stride = 2048; qs = 0.125f*1.44269504f; }
      else            { out = (u16*)C2; cbase = col0 - 2048; stride = 512;  qs = 1.0f; }
      #pragma unroll
      for (int m = 0; m < 2; ++m){
        long r0 = Arow0 + wr*32 + m*16 + l4*4;
        #pragma unroll
        for (int i = 0; i < 4; ++i){
          int s = (int)((r0 + i) & (S_-1));
          const float* cb = cs + s*64 + l15;
          const float* sb = sn + s*64 + l15;
          #pragma unroll
          for (int n = 0; n < 2; ++n){
            float c0 = cb[n*16],      s0v = sb[n*16];
            float c1 = cb[n*16 + 32], s1v = sb[n*16 + 32];
            float t0 = acc[m][n][i], t1 = acc[m][n+2][i];
            long cA = cbase + n*16 + l15;
            out[(r0+i)*stride + cA]      = f2bf((t0*c0 - t1*s0v)*qs);
            out[(r0+i)*stride + cA + 32] = f2bf((t1*c1 + t0*s1v)*qs);
          }
        }
      }
    } else {
      u16* vt = (u16*)C3;
      int g = (int)((col0 - 2560) >> 6);
      #pragma unroll
      for (int m = 0; m < 2; ++m){
        long r0 = Arow0 + wr*32 + m*16 + l4*4;
        int b = (int)(r0 >> 11), s0 = (int)(r0 & (S_-1));
        #pragma unroll
        for (int n = 0; n < 4; ++n){
          int d = n*16 + l15;
          uint2 w;
          w.x = (u32)f2bf(acc[m][n][0]) | ((u32)f2bf(acc[m][n][1])<<16);
          w.y = (u32)f2bf(acc[m][n][2]) | ((u32)f2bf(acc[m][n][3])<<16);
          *(uint2*)(vt + ((long)(b*G_ + g)*64 + d)*S_ + s0) = w;
        }
      }
    }
  }
}

// ---------------- Flash attention: single-buffer K/V, 3 blocks/CU, XCD swizzle ----
// 1-D grid 512; fid&7 clusters the 8 qt-blocks of one (h,b) on one XCD (K/V L2-hot).
// 8 waves, wave owns 32 q-rows, KBLK=64. Q pre-scaled by 0.125*log2e -> p=exp2(s).
// Row-sums l by MFMA against ones (same bf16 P as PV).
__global__ __launch_bounds__(512,6) void k_fattn(const u16* __restrict__ q,
    const u16* __restrict__ k, const u16* __restrict__ vt, u16* __restrict__ o){
  __shared__ u16 Ks[64*64];       // [key][d], slot-swizzled (8 KB)
  __shared__ u16 VTs[64*64];      // [d][key], slot-swizzled (8 KB)
  __shared__ u16 Ps[8][32*64];    // per-wave P [q][key], slot-swizzled (32 KB)
  const int tid = threadIdx.x, lane = tid & 63, wid = tid >> 6;
  const int l15 = lane & 15, l4 = lane >> 4;
  // XCD-swizzled block id decode: all 8 qt of group G land on XCD G&7
  const int fid = blockIdx.x;
  const int G = (fid >> 6)*8 + (fid & 7);   // 0..63 = h + 32*b
  const int qt = (fid >> 3) & 7;
  const int h = G & 31, b = G >> 5;
  const int g = h >> 2;
  const long qrow0 = (long)b*S_ + qt*256 + wid*32;

  s8v aq[2][2];
  #pragma unroll
  for (int mf = 0; mf < 2; ++mf)
    #pragma unroll
    for (int kf = 0; kf < 2; ++kf)
      aq[mf][kf] = *(const s8v*)(q + (qrow0 + mf*16 + l15)*D_ + h*64 + kf*32 + l4*8);

  u4v ov; ov.x = ov.y = ov.z = ov.w = 0x3F803F80u;
  const s8v ones = *(s8v*)&ov;

  const int c = wid*64 + lane;
  const int srow = c >> 3, ko = (c & 7) ^ (srow & 7);
  const u16* ksrc0 = k  + ((long)b*S_ + srow)*KVD + g*64 + ko*8;
  const u16* vsrc0 = vt + ((long)(b*G_ + g)*64 + srow)*S_ + ko*8;

  f4v oacc[2][4] = {};
  f4v lsacc[2] = {};

  for (int kt = 0; kt < S_/64; ++kt){
    // stage tile kt (issued after barrier2 of kt-1 guaranteed all reads done)
    __builtin_amdgcn_global_load_lds(
        (__attribute__((address_space(1))) void*)(void*)(ksrc0 + (long)kt*64*KVD),
        (__attribute__((address_space(3))) void*)(&Ks[wid*512]), 16, 0, 0);
    __builtin_amdgcn_global_load_lds(
        (__attribute__((address_space(1))) void*)(void*)(vsrc0 + kt*64),
        (__attribute__((address_space(3))) void*)(&VTs[wid*512]), 16, 0, 0);
    __syncthreads();                 // loads landed; all waves aligned

    s8v bk[4][2];
    #pragma unroll
    for (int nf = 0; nf < 4; ++nf){
      int key = nf*16 + l15;
      #pragma unroll
      for (int kf = 0; kf < 2; ++kf)
        bk[nf][kf] = *(const s8v*)((const char*)Ks + key*128 + (((kf*4 + l4) ^ (key & 7))<<4));
    }
    f4v sacc[2][4] = {};
    __builtin_amdgcn_s_setprio(1);
    #pragma unroll
    for (int mf = 0; mf < 2; ++mf)
      #pragma unroll
      for (int nf = 0; nf < 4; ++nf)
        #pragma unroll
        for (int kf = 0; kf < 2; ++kf)
          sacc[mf][nf] = __builtin_amdgcn_mfma_f32_16x16x32_bf16(bk[nf][kf], aq[mf][kf], sacc[mf][nf], 0, 0, 0);
    __builtin_amdgcn_s_setprio(0);

    // p = exp2(s) (Q pre-scaled; constant offset cancels in O/l)
    #pragma unroll
    for (int mf = 0; mf < 2; ++mf){
      int r = mf*16 + l15;
      char* pbase = (char*)Ps[wid] + r*128 + (l4 & 1)*8;
      #pragma unroll
      for (int nf = 0; nf < 4; ++nf){
        float p0 = __builtin_amdgcn_exp2f(sacc[mf][nf][0]);
        float p1 = __builtin_amdgcn_exp2f(sacc[mf][nf][1]);
        float p2 = __builtin_amdgcn_exp2f(sacc[mf][nf][2]);
        float p3 = __builtin_amdgcn_exp2f(sacc[mf][nf][3]);
        uint2 w; w.x = pk2bf(p0, p1); w.y = pk2bf(p2, p3);
        int slot = nf*2 + (l4 >> 1);
        *(uint2*)(pbase + ((slot ^ (r & 7))<<4)) = w;
      }
    }

    s8v ap[2][2];
    #pragma unroll
    for (int mf = 0; mf < 2; ++mf){
      int r = mf*16 + l15;
      #pragma unroll
      for (int kf = 0; kf < 2; ++kf)
        ap[mf][kf] = *(const s8v*)((const char*)Ps[wid] + r*128 + (((kf*4 + l4) ^ (r & 7))<<4));
    }
    s8v bv[4][2];
    #pragma unroll
    for (int nd = 0; nd < 4; ++nd){
      int d = nd*16 + l15;
      #pragma unroll
      for (int kf = 0; kf < 2; ++kf)
        bv[nd][kf] = *(const s8v*)((const char*)VTs + d*128 + (((kf*4 + l4) ^ (d & 7))<<4));
    }
    __builtin_amdgcn_s_setprio(1);
    #pragma unroll
    for (int mf = 0; mf < 2; ++mf)
      #pragma unroll
      for (int kf = 0; kf < 2; ++kf)
        lsacc[mf] = __builtin_amdgcn_mfma_f32_16x16x32_bf16(ap[mf][kf], ones, lsacc[mf], 0, 0, 0);
    #pragma unroll
    for (int nd = 0; nd < 4; ++nd)
      #pragma unroll
      for (int kf = 0; kf < 2; ++kf)
        #pragma unroll
        for (int mf = 0; mf < 2; ++mf)
          oacc[mf][nd] = __builtin_amdgcn_mfma_f32_16x16x32_bf16(ap[mf][kf], bv[nd][kf], oacc[mf][nd], 0, 0, 0);
    __builtin_amdgcn_s_setprio(0);
    __syncthreads();                 // all waves done reading Ks/VTs before next stage
  }

  #pragma unroll
  for (int mf = 0; mf < 2; ++mf){
    f4v li;
    #pragma unroll
    for (int i = 0; i < 4; ++i) li[i] = 1.f / lsacc[mf][i];
    #pragma unroll
    for (int nd = 0; nd < 4; ++nd){
      long r = qrow0 + mf*16 + l4*4;
      int cc = h*64 + nd*16 + l15;
      o[(r+0)*D_ + cc] = f2bf(oacc[mf][nd][0]*li[0]);
      o[(r+1)*D_ + cc] = f2bf(oacc[mf][nd][1]*li[1]);
      o[(r+2)*D_ + cc] = f2bf(oacc[mf][nd][2]*li[2]);
      o[(r+3)*D_ + cc] = f2bf(oacc[mf][nd][3]*li[3]);
    }
  }
}

extern "C" void kernel_launch(void* const* d_in, const int* in_sizes, int n_in,
                              void* d_out, int out_size, void* d_ws, size_t ws_size,
                              hipStream_t stream){
  const float* x    = (const float*)d_in[0];
  const float* cosp = (const float*)d_in[1];
  const float* sinp = (const float*)d_in[2];
  const float* Wq = (const float*)d_in[4];
  const float* Wk = (const float*)d_in[5];
  const float* Wv = (const float*)d_in[6];
  const float* Wo = (const float*)d_in[7];

  char* ws = (char*)d_ws;
  size_t off = 0;
  auto alloc = [&](size_t bytes)->char*{
    char* p = ws + off; off += (bytes + 255) & ~(size_t)255; return p;
  };
  u16* xb    = (u16*)alloc((size_t)8388608*2);
  u16* wqkvb = (u16*)alloc((size_t)6291456*2);   // [3072][2048] = Wq|Wk|Wv rows
  u16* wob   = (u16*)alloc((size_t)4194304*2);
  u16* qb    = (u16*)alloc((size_t)8388608*2);
  u16* kb    = (u16*)alloc((size_t)2097152*2);   // B*S x KVD = 4096 x 512
  u16* vtb   = (u16*)alloc((size_t)2097152*2);   // B*G x 64 x S
  u16* ab    = (u16*)alloc((size_t)8388608*2);
  if (ws_size < off) return;

  CvtArgs ca{ x, Wq, Wk, Wv, Wo, xb, wqkvb, wob };
  k_cvt5<<<2048,256,0,stream>>>(ca);

  // fused QKV projection: M=4096, N=3072, epilogue routes per col-range
  k_gemm<3><<<dim3(32,24,1),512,0,stream>>>(xb, wqkvb, qb, kb, vtb, cosp, sinp, 3072, 2048);

  k_fattn<<<dim3(512,1,1),512,0,stream>>>(qb, kb, vtb, ab);

  // output projection -> fp32 d_out
  k_gemm<0><<<dim3(32,16,1),512,0,stream>>>(ab, wob, d_out, nullptr, nullptr, nullptr, nullptr, 2048, 2048);
}

// Round 15
// 206.875 us; speedup vs baseline: 2.4653x; 2.4653x over previous
//
#include <hip/hip_runtime.h>
#include <hip/hip_bf16.h>
#include <stdint.h>

#define B_ 2
#define S_ 2048
#define D_ 2048
#define H_ 32
#define G_ 8
#define HD_ 64
#define KVD (G_*HD_)   // 512

typedef unsigned short u16;
typedef unsigned int u32;
typedef __attribute__((ext_vector_type(8))) short s8v;
typedef __attribute__((ext_vector_type(4))) float f4v;
typedef __attribute__((ext_vector_type(4))) unsigned int u4v;

static __device__ __forceinline__ float bf2f(u16 u){ return __uint_as_float(((u32)u)<<16); }
static __device__ __forceinline__ u16 f2bf(float f){
  u32 b = __float_as_uint(f);
  return (u16)((b + 0x7FFFu + ((b>>16)&1u)) >> 16);
}
static __device__ __forceinline__ u32 pk2bf(float a, float b){
  float2 f2 = make_float2(a, b);
  __hip_bfloat162 h = __float22bfloat162_rn(f2);
  return *(u32*)&h;
}

// ---- fused fp32 -> bf16 convert: x, Wq|Wk|Wv (concatenated 3072x2048), Wo ----
struct CvtArgs {
  const float *x, *wq, *wk, *wv, *wo;
  u16 *xb, *wqkvb, *wob;
};
__global__ void k_cvt5(CvtArgs a){
  const int E0 = 2097152;            // x  (2097152 f4)
  const int E1 = E0 + 1048576;       // Wq
  const int E2 = E1 + 262144;        // Wk
  const int E3 = E2 + 262144;        // Wv
  const int E4 = E3 + 1048576;       // Wo
  int u = blockIdx.x*blockDim.x + threadIdx.x;
  int stride = gridDim.x*blockDim.x;
  for (; u < E4; u += stride){
    const float* s; u16* d; int off;
    if      (u < E0){ s = a.x;  d = a.xb;               off = u; }
    else if (u < E1){ s = a.wq; d = a.wqkvb;            off = u - E0; }
    else if (u < E2){ s = a.wk; d = a.wqkvb + 4194304;  off = u - E1; }
    else if (u < E3){ s = a.wv; d = a.wqkvb + 5242880;  off = u - E2; }
    else            { s = a.wo; d = a.wob;              off = u - E3; }
    float4 f = *(const float4*)(s + (long)off*4);
    uint2 o;
    o.x = (u32)f2bf(f.x) | ((u32)f2bf(f.y)<<16);
    o.y = (u32)f2bf(f.z) | ((u32)f2bf(f.w)<<16);
    *(uint2*)(d + (long)off*4) = o;
  }
}

// ---------------- GEMM: C[m][n] = sum_k A[m][k] * W[n][k], K=2048 ----------------
// 8 waves per 128x128 tile (wave owns 32x64); double-buffered staging.
// MODE 0: f32 store (O-proj) into C.
// MODE 3: QKV-fused epilogue by col-range: [0,2048) rope*C1 -> C(qb, stride 2048);
//         [2048,2560) rope -> C2(kb, stride 512); [2560,3072) transpose -> C3(vtb).
// Q is pre-scaled by C1 = 0.125*log2(e) so fattn's softmax is exp2(s) directly.
template<int MODE>
__global__ __launch_bounds__(512) void k_gemm(const u16* __restrict__ A,
    const u16* __restrict__ Bw,
    void* __restrict__ C, void* __restrict__ C2, void* __restrict__ C3,
    const float* __restrict__ cs, const float* __restrict__ sn,
    int N_unused, int K){
  __shared__ u16 As[2][128*32];
  __shared__ u16 Bs[2][128*32];
  const int tid = threadIdx.x;
  const int lane = tid & 63, wid = tid >> 6;
  const int l15 = lane & 15, l4 = lane >> 4;
  const int wr = wid >> 1, wc = wid & 1;     // 4x2 wave grid; wave tile 32x64
  const long Arow0 = (long)blockIdx.x * 128;
  const long Brow0 = (long)blockIdx.y * 128;
  const int NKS = K >> 5;

  const int sc = tid;
  const int srow = sc >> 2, slot = sc & 3;
  const int ko = slot ^ (srow & 3);
  const u16* srcA0 = A  + (Arow0 + srow)*K + ko*8;
  const u16* srcB0 = Bw + (Brow0 + srow)*K + ko*8;
  auto stage = [&](int ks){
    int bsel = ks & 1, k0 = ks << 5;
    __builtin_amdgcn_global_load_lds(
        (__attribute__((address_space(1))) void*)(void*)(srcA0 + k0),
        (__attribute__((address_space(3))) void*)(&As[bsel][wid*512]), 16, 0, 0);
    __builtin_amdgcn_global_load_lds(
        (__attribute__((address_space(1))) void*)(void*)(srcB0 + k0),
        (__attribute__((address_space(3))) void*)(&Bs[bsel][wid*512]), 16, 0, 0);
  };

  f4v acc[2][4] = {};
  stage(0);
  for (int ks = 0; ks < NKS; ++ks){
    __syncthreads();                 // drains loads staged one iteration ago
    if (ks + 1 < NKS) stage(ks + 1);
    const u16* AsB = As[ks & 1];
    const u16* BsB = Bs[ks & 1];
    s8v af[2], bf[4];
    #pragma unroll
    for (int m = 0; m < 2; ++m){
      int row = wr*32 + m*16 + l15;
      af[m] = *(const s8v*)((const char*)AsB + row*64 + ((l4 ^ (row & 3))<<4));
    }
    #pragma unroll
    for (int n = 0; n < 4; ++n){
      int col = wc*64 + n*16 + l15;
      bf[n] = *(const s8v*)((const char*)BsB + col*64 + ((l4 ^ (col & 3))<<4));
    }
    __builtin_amdgcn_s_setprio(1);
    #pragma unroll
    for (int m = 0; m < 2; ++m)
      #pragma unroll
      for (int n = 0; n < 4; ++n)
        acc[m][n] = __builtin_amdgcn_mfma_f32_16x16x32_bf16(af[m], bf[n], acc[m][n], 0, 0, 0);
    __builtin_amdgcn_s_setprio(0);
  }

  if (MODE == 0){
    #pragma unroll
    for (int m = 0; m < 2; ++m)
      #pragma unroll
      for (int n = 0; n < 4; ++n)
        #pragma unroll
        for (int i = 0; i < 4; ++i){
          long r = Arow0 + wr*32 + m*16 + l4*4 + i;
          long c = Brow0 + wc*64 + n*16 + l15;
          ((float*)C)[r*2048 + c] = acc[m][n][i];
        }
  } else {
    const long col0 = Brow0 + wc*64;   // 64-aligned; wave's region in one segment
    if (col0 < 2560){
      u16* out; long cbase; int stride; float qs;
      if (col0 < 2048){ out = (u16*)C;  cbase = col0;        stride = 2048; qs = 0.125f*1.44269504f; }
      else            { out = (u16*)C2; cbase = col0 - 2048; stride = 512;  qs = 1.0f; }
      #pragma unroll
      for (int m = 0; m < 2; ++m){
        long r0 = Arow0 + wr*32 + m*16 + l4*4;
        #pragma unroll
        for (int i = 0; i < 4; ++i){
          int s = (int)((r0 + i) & (S_-1));
          const float* cb = cs + s*64 + l15;
          const float* sb = sn + s*64 + l15;
          #pragma unroll
          for (int n = 0; n < 2; ++n){
            float c0 = cb[n*16],      s0v = sb[n*16];
            float c1 = cb[n*16 + 32], s1v = sb[n*16 + 32];
            float t0 = acc[m][n][i], t1 = acc[m][n+2][i];
            long cA = cbase + n*16 + l15;
            out[(r0+i)*stride + cA]      = f2bf((t0*c0 - t1*s0v)*qs);
            out[(r0+i)*stride + cA + 32] = f2bf((t1*c1 + t0*s1v)*qs);
          }
        }
      }
    } else {
      u16* vt = (u16*)C3;
      int g = (int)((col0 - 2560) >> 6);
      #pragma unroll
      for (int m = 0; m < 2; ++m){
        long r0 = Arow0 + wr*32 + m*16 + l4*4;
        int b = (int)(r0 >> 11), s0 = (int)(r0 & (S_-1));
        #pragma unroll
        for (int n = 0; n < 4; ++n){
          int d = n*16 + l15;
          uint2 w;
          w.x = (u32)f2bf(acc[m][n][0]) | ((u32)f2bf(acc[m][n][1])<<16);
          w.y = (u32)f2bf(acc[m][n][2]) | ((u32)f2bf(acc[m][n][3])<<16);
          *(uint2*)(vt + ((long)(b*G_ + g)*64 + d)*S_ + s0) = w;
        }
      }
    }
  }
}

// ---------------- Flash attention (R13 structure + XCD swizzle) ----------------
// 1-D grid 512; fid&7 clusters the 8 qt-blocks of one (h,b) on one XCD (K/V L2-hot).
// 8 waves, wave owns 32 q-rows, KBLK=64, dbuf + syncthreads (proven R13 structure).
// Q pre-scaled by 0.125*log2e -> p = exp2(s); row-sums l by MFMA against ones.
__global__ __launch_bounds__(512) void k_fattn(const u16* __restrict__ q,
    const u16* __restrict__ k, const u16* __restrict__ vt, u16* __restrict__ o){
  __shared__ u16 Ks[2][64*64];    // [key][d], slot-swizzled
  __shared__ u16 VTs[2][64*64];   // [d][key], slot-swizzled
  __shared__ u16 Ps[8][32*64];    // per-wave P [q][key], slot-swizzled
  const int tid = threadIdx.x, lane = tid & 63, wid = tid >> 6;
  const int l15 = lane & 15, l4 = lane >> 4;
  // XCD-swizzled block id decode: all 8 qt of group G land on XCD G&7
  const int fid = blockIdx.x;
  const int G = (fid >> 6)*8 + (fid & 7);   // 0..63 = h + 32*b
  const int qt = (fid >> 3) & 7;
  const int h = G & 31, b = G >> 5;
  const int g = h >> 2;
  const long qrow0 = (long)b*S_ + qt*256 + wid*32;

  s8v aq[2][2];
  #pragma unroll
  for (int mf = 0; mf < 2; ++mf)
    #pragma unroll
    for (int kf = 0; kf < 2; ++kf)
      aq[mf][kf] = *(const s8v*)(q + (qrow0 + mf*16 + l15)*D_ + h*64 + kf*32 + l4*8);

  // ones B-operand (bf16 1.0 x8) for row-sum MFMA
  u4v ov; ov.x = ov.y = ov.z = ov.w = 0x3F803F80u;
  const s8v ones = *(s8v*)&ov;

  const int c = wid*64 + lane;
  const int srow = c >> 3, ko = (c & 7) ^ (srow & 7);
  const u16* ksrc0 = k  + ((long)b*S_ + srow)*KVD + g*64 + ko*8;
  const u16* vsrc0 = vt + ((long)(b*G_ + g)*64 + srow)*S_ + ko*8;

  auto stage = [&](int kt){
    int bsel = kt & 1;
    __builtin_amdgcn_global_load_lds(
        (__attribute__((address_space(1))) void*)(void*)(ksrc0 + (long)kt*64*KVD),
        (__attribute__((address_space(3))) void*)(&Ks[bsel][wid*512]), 16, 0, 0);
    __builtin_amdgcn_global_load_lds(
        (__attribute__((address_space(1))) void*)(void*)(vsrc0 + kt*64),
        (__attribute__((address_space(3))) void*)(&VTs[bsel][wid*512]), 16, 0, 0);
  };

  f4v oacc[2][4] = {};
  f4v lsacc[2] = {};

  stage(0);
  for (int kt = 0; kt < S_/64; ++kt){
    __syncthreads();                 // drains vmcnt: tile kt ready; buf[(kt+1)&1] free
    if (kt + 1 < S_/64) stage(kt + 1);
    const u16* KsB = Ks[kt & 1];
    const u16* VsB = VTs[kt & 1];

    s8v bk[4][2];
    #pragma unroll
    for (int nf = 0; nf < 4; ++nf){
      int key = nf*16 + l15;
      #pragma unroll
      for (int kf = 0; kf < 2; ++kf)
        bk[nf][kf] = *(const s8v*)((const char*)KsB + key*128 + (((kf*4 + l4) ^ (key & 7))<<4));
    }
    f4v sacc[2][4] = {};
    __builtin_amdgcn_s_setprio(1);
    #pragma unroll
    for (int mf = 0; mf < 2; ++mf)
      #pragma unroll
      for (int nf = 0; nf < 4; ++nf)
        #pragma unroll
        for (int kf = 0; kf < 2; ++kf)
          sacc[mf][nf] = __builtin_amdgcn_mfma_f32_16x16x32_bf16(bk[nf][kf], aq[mf][kf], sacc[mf][nf], 0, 0, 0);
    __builtin_amdgcn_s_setprio(0);

    // p = exp2(s) (Q pre-scaled; constant offset cancels in O/l)
    #pragma unroll
    for (int mf = 0; mf < 2; ++mf){
      int r = mf*16 + l15;
      char* pbase = (char*)Ps[wid] + r*128 + (l4 & 1)*8;
      #pragma unroll
      for (int nf = 0; nf < 4; ++nf){
        float p0 = __builtin_amdgcn_exp2f(sacc[mf][nf][0]);
        float p1 = __builtin_amdgcn_exp2f(sacc[mf][nf][1]);
        float p2 = __builtin_amdgcn_exp2f(sacc[mf][nf][2]);
        float p3 = __builtin_amdgcn_exp2f(sacc[mf][nf][3]);
        uint2 w; w.x = pk2bf(p0, p1); w.y = pk2bf(p2, p3);
        int slot = nf*2 + (l4 >> 1);
        *(uint2*)(pbase + ((slot ^ (r & 7))<<4)) = w;
      }
    }

    s8v ap[2][2];
    #pragma unroll
    for (int mf = 0; mf < 2; ++mf){
      int r = mf*16 + l15;
      #pragma unroll
      for (int kf = 0; kf < 2; ++kf)
        ap[mf][kf] = *(const s8v*)((const char*)Ps[wid] + r*128 + (((kf*4 + l4) ^ (r & 7))<<4));
    }
    __builtin_amdgcn_s_setprio(1);
    // row-sums on the matrix pipe: lsacc[mf][i] = sum_k P[row l4*4+i][k]
    #pragma unroll
    for (int mf = 0; mf < 2; ++mf)
      #pragma unroll
      for (int kf = 0; kf < 2; ++kf)
        lsacc[mf] = __builtin_amdgcn_mfma_f32_16x16x32_bf16(ap[mf][kf], ones, lsacc[mf], 0, 0, 0);
    #pragma unroll
    for (int nd = 0; nd < 4; ++nd){
      int d = nd*16 + l15;
      #pragma unroll
      for (int kf = 0; kf < 2; ++kf){
        s8v bv = *(const s8v*)((const char*)VsB + d*128 + (((kf*4 + l4) ^ (d & 7))<<4));
        #pragma unroll
        for (int mf = 0; mf < 2; ++mf)
          oacc[mf][nd] = __builtin_amdgcn_mfma_f32_16x16x32_bf16(ap[mf][kf], bv, oacc[mf][nd], 0, 0, 0);
      }
    }
    __builtin_amdgcn_s_setprio(0);
  }

  // lane already holds its rows' full sums in lsacc[mf][i] — no shuffles needed
  #pragma unroll
  for (int mf = 0; mf < 2; ++mf){
    f4v li;
    #pragma unroll
    for (int i = 0; i < 4; ++i) li[i] = 1.f / lsacc[mf][i];
    #pragma unroll
    for (int nd = 0; nd < 4; ++nd){
      long r = qrow0 + mf*16 + l4*4;
      int cc = h*64 + nd*16 + l15;
      o[(r+0)*D_ + cc] = f2bf(oacc[mf][nd][0]*li[0]);
      o[(r+1)*D_ + cc] = f2bf(oacc[mf][nd][1]*li[1]);
      o[(r+2)*D_ + cc] = f2bf(oacc[mf][nd][2]*li[2]);
      o[(r+3)*D_ + cc] = f2bf(oacc[mf][nd][3]*li[3]);
    }
  }
}

extern "C" void kernel_launch(void* const* d_in, const int* in_sizes, int n_in,
                              void* d_out, int out_size, void* d_ws, size_t ws_size,
                              hipStream_t stream){
  const float* x    = (const float*)d_in[0];
  const float* cosp = (const float*)d_in[1];
  const float* sinp = (const float*)d_in[2];
  const float* Wq = (const float*)d_in[4];
  const float* Wk = (const float*)d_in[5];
  const float* Wv = (const float*)d_in[6];
  const float* Wo = (const float*)d_in[7];

  char* ws = (char*)d_ws;
  size_t off = 0;
  auto alloc = [&](size_t bytes)->char*{
    char* p = ws + off; off += (bytes + 255) & ~(size_t)255; return p;
  };
  u16* xb    = (u16*)alloc((size_t)8388608*2);
  u16* wqkvb = (u16*)alloc((size_t)6291456*2);   // [3072][2048] = Wq|Wk|Wv rows
  u16* wob   = (u16*)alloc((size_t)4194304*2);
  u16* qb    = (u16*)alloc((size_t)8388608*2);
  u16* kb    = (u16*)alloc((size_t)2097152*2);   // B*S x KVD = 4096 x 512
  u16* vtb   = (u16*)alloc((size_t)2097152*2);   // B*G x 64 x S
  u16* ab    = (u16*)alloc((size_t)8388608*2);
  if (ws_size < off) return;

  CvtArgs ca{ x, Wq, Wk, Wv, Wo, xb, wqkvb, wob };
  k_cvt5<<<2048,256,0,stream>>>(ca);

  // fused QKV projection: M=4096, N=3072, epilogue routes per col-range
  k_gemm<3><<<dim3(32,24,1),512,0,stream>>>(xb, wqkvb, qb, kb, vtb, cosp, sinp, 3072, 2048);

  k_fattn<<<dim3(512,1,1),512,0,stream>>>(qb, kb, vtb, ab);

  // output projection -> fp32 d_out
  k_gemm<0><<<dim3(32,16,1),512,0,stream>>>(ab, wob, d_out, nullptr, nullptr, nullptr, nullptr, 2048, 2048);
}

// Round 16
// 206.547 us; speedup vs baseline: 2.4693x; 1.0016x over previous
//
#include <hip/hip_runtime.h>
#include <hip/hip_bf16.h>
#include <stdint.h>

#define B_ 2
#define S_ 2048
#define D_ 2048
#define H_ 32
#define G_ 8
#define HD_ 64
#define KVD (G_*HD_)   // 512

typedef unsigned short u16;
typedef unsigned int u32;
typedef __attribute__((ext_vector_type(8))) short s8v;
typedef __attribute__((ext_vector_type(4))) float f4v;
typedef __attribute__((ext_vector_type(4))) unsigned int u4v;

static __device__ __forceinline__ float bf2f(u16 u){ return __uint_as_float(((u32)u)<<16); }
static __device__ __forceinline__ u16 f2bf(float f){
  u32 b = __float_as_uint(f);
  return (u16)((b + 0x7FFFu + ((b>>16)&1u)) >> 16);
}
static __device__ __forceinline__ u32 pk2bf(float a, float b){
  float2 f2 = make_float2(a, b);
  __hip_bfloat162 h = __float22bfloat162_rn(f2);
  return *(u32*)&h;
}

// ---- fused fp32 -> bf16 convert: x, Wq|Wk|Wv (concatenated 3072x2048), Wo ----
struct CvtArgs {
  const float *x, *wq, *wk, *wv, *wo;
  u16 *xb, *wqkvb, *wob;
};
__global__ void k_cvt5(CvtArgs a){
  const int E0 = 2097152;            // x  (2097152 f4)
  const int E1 = E0 + 1048576;       // Wq
  const int E2 = E1 + 262144;        // Wk
  const int E3 = E2 + 262144;        // Wv
  const int E4 = E3 + 1048576;       // Wo
  int u = blockIdx.x*blockDim.x + threadIdx.x;
  int stride = gridDim.x*blockDim.x;
  for (; u < E4; u += stride){
    const float* s; u16* d; int off;
    if      (u < E0){ s = a.x;  d = a.xb;               off = u; }
    else if (u < E1){ s = a.wq; d = a.wqkvb;            off = u - E0; }
    else if (u < E2){ s = a.wk; d = a.wqkvb + 4194304;  off = u - E1; }
    else if (u < E3){ s = a.wv; d = a.wqkvb + 5242880;  off = u - E2; }
    else            { s = a.wo; d = a.wob;              off = u - E3; }
    float4 f = *(const float4*)(s + (long)off*4);
    uint2 o;
    o.x = (u32)f2bf(f.x) | ((u32)f2bf(f.y)<<16);
    o.y = (u32)f2bf(f.z) | ((u32)f2bf(f.w)<<16);
    *(uint2*)(d + (long)off*4) = o;
  }
}

// ---------------- GEMM: C[m][n] = sum_k A[m][k] * W[n][k], K=2048 ----------------
// 8 waves per 128x128 tile (wave owns 32x64); double-buffered staging.
// MODE 0: f32 store (O-proj) into C.
// MODE 3: QKV-fused epilogue by col-range: [0,2048) rope*C1 -> C(qb, stride 2048);
//         [2048,2560) rope -> C2(kb, stride 512); [2560,3072) transpose -> C3(vtb).
// Q is pre-scaled by C1 = 0.125*log2(e) so fattn's softmax is exp2(s) directly.
template<int MODE>
__global__ __launch_bounds__(512) void k_gemm(const u16* __restrict__ A,
    const u16* __restrict__ Bw,
    void* __restrict__ C, void* __restrict__ C2, void* __restrict__ C3,
    const float* __restrict__ cs, const float* __restrict__ sn,
    int N_unused, int K){
  __shared__ u16 As[2][128*32];
  __shared__ u16 Bs[2][128*32];
  const int tid = threadIdx.x;
  const int lane = tid & 63, wid = tid >> 6;
  const int l15 = lane & 15, l4 = lane >> 4;
  const int wr = wid >> 1, wc = wid & 1;     // 4x2 wave grid; wave tile 32x64
  const long Arow0 = (long)blockIdx.x * 128;
  const long Brow0 = (long)blockIdx.y * 128;
  const int NKS = K >> 5;

  const int sc = tid;
  const int srow = sc >> 2, slot = sc & 3;
  const int ko = slot ^ (srow & 3);
  const u16* srcA0 = A  + (Arow0 + srow)*K + ko*8;
  const u16* srcB0 = Bw + (Brow0 + srow)*K + ko*8;
  auto stage = [&](int ks){
    int bsel = ks & 1, k0 = ks << 5;
    __builtin_amdgcn_global_load_lds(
        (__attribute__((address_space(1))) void*)(void*)(srcA0 + k0),
        (__attribute__((address_space(3))) void*)(&As[bsel][wid*512]), 16, 0, 0);
    __builtin_amdgcn_global_load_lds(
        (__attribute__((address_space(1))) void*)(void*)(srcB0 + k0),
        (__attribute__((address_space(3))) void*)(&Bs[bsel][wid*512]), 16, 0, 0);
  };

  f4v acc[2][4] = {};
  stage(0);
  for (int ks = 0; ks < NKS; ++ks){
    __syncthreads();                 // drains loads staged one iteration ago
    if (ks + 1 < NKS) stage(ks + 1);
    const u16* AsB = As[ks & 1];
    const u16* BsB = Bs[ks & 1];
    s8v af[2], bf[4];
    #pragma unroll
    for (int m = 0; m < 2; ++m){
      int row = wr*32 + m*16 + l15;
      af[m] = *(const s8v*)((const char*)AsB + row*64 + ((l4 ^ (row & 3))<<4));
    }
    #pragma unroll
    for (int n = 0; n < 4; ++n){
      int col = wc*64 + n*16 + l15;
      bf[n] = *(const s8v*)((const char*)BsB + col*64 + ((l4 ^ (col & 3))<<4));
    }
    __builtin_amdgcn_s_setprio(1);
    #pragma unroll
    for (int m = 0; m < 2; ++m)
      #pragma unroll
      for (int n = 0; n < 4; ++n)
        acc[m][n] = __builtin_amdgcn_mfma_f32_16x16x32_bf16(af[m], bf[n], acc[m][n], 0, 0, 0);
    __builtin_amdgcn_s_setprio(0);
  }

  if (MODE == 0){
    #pragma unroll
    for (int m = 0; m < 2; ++m)
      #pragma unroll
      for (int n = 0; n < 4; ++n)
        #pragma unroll
        for (int i = 0; i < 4; ++i){
          long r = Arow0 + wr*32 + m*16 + l4*4 + i;
          long c = Brow0 + wc*64 + n*16 + l15;
          ((float*)C)[r*2048 + c] = acc[m][n][i];
        }
  } else {
    const long col0 = Brow0 + wc*64;   // 64-aligned; wave's region in one segment
    if (col0 < 2560){
      u16* out; long cbase; int stride; float qs;
      if (col0 < 2048){ out = (u16*)C;  cbase = col0;        stride = 2048; qs = 0.125f*1.44269504f; }
      else            { out = (u16*)C2; cbase = col0 - 2048; stride = 512;  qs = 1.0f; }
      #pragma unroll
      for (int m = 0; m < 2; ++m){
        long r0 = Arow0 + wr*32 + m*16 + l4*4;
        #pragma unroll
        for (int i = 0; i < 4; ++i){
          int s = (int)((r0 + i) & (S_-1));
          const float* cb = cs + s*64 + l15;
          const float* sb = sn + s*64 + l15;
          #pragma unroll
          for (int n = 0; n < 2; ++n){
            float c0 = cb[n*16],      s0v = sb[n*16];
            float c1 = cb[n*16 + 32], s1v = sb[n*16 + 32];
            float t0 = acc[m][n][i], t1 = acc[m][n+2][i];
            long cA = cbase + n*16 + l15;
            out[(r0+i)*stride + cA]      = f2bf((t0*c0 - t1*s0v)*qs);
            out[(r0+i)*stride + cA + 32] = f2bf((t1*c1 + t0*s1v)*qs);
          }
        }
      }
    } else {
      u16* vt = (u16*)C3;
      int g = (int)((col0 - 2560) >> 6);
      #pragma unroll
      for (int m = 0; m < 2; ++m){
        long r0 = Arow0 + wr*32 + m*16 + l4*4;
        int b = (int)(r0 >> 11), s0 = (int)(r0 & (S_-1));
        #pragma unroll
        for (int n = 0; n < 4; ++n){
          int d = n*16 + l15;
          uint2 w;
          w.x = (u32)f2bf(acc[m][n][0]) | ((u32)f2bf(acc[m][n][1])<<16);
          w.y = (u32)f2bf(acc[m][n][2]) | ((u32)f2bf(acc[m][n][3])<<16);
          *(uint2*)(vt + ((long)(b*G_ + g)*64 + d)*S_ + s0) = w;
        }
      }
    }
  }
}

// ---------------- Flash attention: single-buffer K/V (48 KB -> 3 blocks/CU) ----
// 1-D grid 512; fid&7 clusters the 8 qt-blocks of one (h,b) on one XCD (K/V L2-hot,
// proven R15: FETCH 41->24.6 MB). 8 waves, wave owns 32 q-rows, KBLK=64.
// Q pre-scaled by 0.125*log2e -> p = exp2(s); row-sums l by MFMA against ones.
// NOTE: plain launch_bounds + inline bv reads — R14's spill came from (512,6)+bv array.
__global__ __launch_bounds__(512) void k_fattn(const u16* __restrict__ q,
    const u16* __restrict__ k, const u16* __restrict__ vt, u16* __restrict__ o){
  __shared__ u16 Ks[64*64];       // [key][d], slot-swizzled (8 KB)
  __shared__ u16 VTs[64*64];      // [d][key], slot-swizzled (8 KB)
  __shared__ u16 Ps[8][32*64];    // per-wave P [q][key], slot-swizzled (32 KB)
  const int tid = threadIdx.x, lane = tid & 63, wid = tid >> 6;
  const int l15 = lane & 15, l4 = lane >> 4;
  // XCD-swizzled block id decode: all 8 qt of group G land on XCD G&7
  const int fid = blockIdx.x;
  const int G = (fid >> 6)*8 + (fid & 7);   // 0..63 = h + 32*b
  const int qt = (fid >> 3) & 7;
  const int h = G & 31, b = G >> 5;
  const int g = h >> 2;
  const long qrow0 = (long)b*S_ + qt*256 + wid*32;

  s8v aq[2][2];
  #pragma unroll
  for (int mf = 0; mf < 2; ++mf)
    #pragma unroll
    for (int kf = 0; kf < 2; ++kf)
      aq[mf][kf] = *(const s8v*)(q + (qrow0 + mf*16 + l15)*D_ + h*64 + kf*32 + l4*8);

  // ones B-operand (bf16 1.0 x8) for row-sum MFMA
  u4v ov; ov.x = ov.y = ov.z = ov.w = 0x3F803F80u;
  const s8v ones = *(s8v*)&ov;

  const int c = wid*64 + lane;
  const int srow = c >> 3, ko = (c & 7) ^ (srow & 7);
  const u16* ksrc0 = k  + ((long)b*S_ + srow)*KVD + g*64 + ko*8;
  const u16* vsrc0 = vt + ((long)(b*G_ + g)*64 + srow)*S_ + ko*8;

  f4v oacc[2][4] = {};
  f4v lsacc[2] = {};

  for (int kt = 0; kt < S_/64; ++kt){
    // issue tile kt; prior iteration's trailing barrier guarantees reads are done
    __builtin_amdgcn_global_load_lds(
        (__attribute__((address_space(1))) void*)(void*)(ksrc0 + (long)kt*64*KVD),
        (__attribute__((address_space(3))) void*)(&Ks[wid*512]), 16, 0, 0);
    __builtin_amdgcn_global_load_lds(
        (__attribute__((address_space(1))) void*)(void*)(vsrc0 + kt*64),
        (__attribute__((address_space(3))) void*)(&VTs[wid*512]), 16, 0, 0);
    __syncthreads();                 // loads landed

    s8v bk[4][2];
    #pragma unroll
    for (int nf = 0; nf < 4; ++nf){
      int key = nf*16 + l15;
      #pragma unroll
      for (int kf = 0; kf < 2; ++kf)
        bk[nf][kf] = *(const s8v*)((const char*)Ks + key*128 + (((kf*4 + l4) ^ (key & 7))<<4));
    }
    f4v sacc[2][4] = {};
    __builtin_amdgcn_s_setprio(1);
    #pragma unroll
    for (int mf = 0; mf < 2; ++mf)
      #pragma unroll
      for (int nf = 0; nf < 4; ++nf)
        #pragma unroll
        for (int kf = 0; kf < 2; ++kf)
          sacc[mf][nf] = __builtin_amdgcn_mfma_f32_16x16x32_bf16(bk[nf][kf], aq[mf][kf], sacc[mf][nf], 0, 0, 0);
    __builtin_amdgcn_s_setprio(0);

    // p = exp2(s) (Q pre-scaled; constant offset cancels in O/l)
    #pragma unroll
    for (int mf = 0; mf < 2; ++mf){
      int r = mf*16 + l15;
      char* pbase = (char*)Ps[wid] + r*128 + (l4 & 1)*8;
      #pragma unroll
      for (int nf = 0; nf < 4; ++nf){
        float p0 = __builtin_amdgcn_exp2f(sacc[mf][nf][0]);
        float p1 = __builtin_amdgcn_exp2f(sacc[mf][nf][1]);
        float p2 = __builtin_amdgcn_exp2f(sacc[mf][nf][2]);
        float p3 = __builtin_amdgcn_exp2f(sacc[mf][nf][3]);
        uint2 w; w.x = pk2bf(p0, p1); w.y = pk2bf(p2, p3);
        int slot = nf*2 + (l4 >> 1);
        *(uint2*)(pbase + ((slot ^ (r & 7))<<4)) = w;
      }
    }

    s8v ap[2][2];
    #pragma unroll
    for (int mf = 0; mf < 2; ++mf){
      int r = mf*16 + l15;
      #pragma unroll
      for (int kf = 0; kf < 2; ++kf)
        ap[mf][kf] = *(const s8v*)((const char*)Ps[wid] + r*128 + (((kf*4 + l4) ^ (r & 7))<<4));
    }
    __builtin_amdgcn_s_setprio(1);
    // row-sums on the matrix pipe: lsacc[mf][i] = sum_k P[row l4*4+i][k]
    #pragma unroll
    for (int mf = 0; mf < 2; ++mf)
      #pragma unroll
      for (int kf = 0; kf < 2; ++kf)
        lsacc[mf] = __builtin_amdgcn_mfma_f32_16x16x32_bf16(ap[mf][kf], ones, lsacc[mf], 0, 0, 0);
    #pragma unroll
    for (int nd = 0; nd < 4; ++nd){
      int d = nd*16 + l15;
      #pragma unroll
      for (int kf = 0; kf < 2; ++kf){
        s8v bv = *(const s8v*)((const char*)VTs + d*128 + (((kf*4 + l4) ^ (d & 7))<<4));
        #pragma unroll
        for (int mf = 0; mf < 2; ++mf)
          oacc[mf][nd] = __builtin_amdgcn_mfma_f32_16x16x32_bf16(ap[mf][kf], bv, oacc[mf][nd], 0, 0, 0);
      }
    }
    __builtin_amdgcn_s_setprio(0);
    __syncthreads();                 // all waves done reading Ks/VTs before next stage
  }

  // lane already holds its rows' full sums in lsacc[mf][i] — no shuffles needed
  #pragma unroll
  for (int mf = 0; mf < 2; ++mf){
    f4v li;
    #pragma unroll
    for (int i = 0; i < 4; ++i) li[i] = 1.f / lsacc[mf][i];
    #pragma unroll
    for (int nd = 0; nd < 4; ++nd){
      long r = qrow0 + mf*16 + l4*4;
      int cc = h*64 + nd*16 + l15;
      o[(r+0)*D_ + cc] = f2bf(oacc[mf][nd][0]*li[0]);
      o[(r+1)*D_ + cc] = f2bf(oacc[mf][nd][1]*li[1]);
      o[(r+2)*D_ + cc] = f2bf(oacc[mf][nd][2]*li[2]);
      o[(r+3)*D_ + cc] = f2bf(oacc[mf][nd][3]*li[3]);
    }
  }
}

extern "C" void kernel_launch(void* const* d_in, const int* in_sizes, int n_in,
                              void* d_out, int out_size, void* d_ws, size_t ws_size,
                              hipStream_t stream){
  const float* x    = (const float*)d_in[0];
  const float* cosp = (const float*)d_in[1];
  const float* sinp = (const float*)d_in[2];
  const float* Wq = (const float*)d_in[4];
  const float* Wk = (const float*)d_in[5];
  const float* Wv = (const float*)d_in[6];
  const float* Wo = (const float*)d_in[7];

  char* ws = (char*)d_ws;
  size_t off = 0;
  auto alloc = [&](size_t bytes)->char*{
    char* p = ws + off; off += (bytes + 255) & ~(size_t)255; return p;
  };
  u16* xb    = (u16*)alloc((size_t)8388608*2);
  u16* wqkvb = (u16*)alloc((size_t)6291456*2);   // [3072][2048] = Wq|Wk|Wv rows
  u16* wob   = (u16*)alloc((size_t)4194304*2);
  u16* qb    = (u16*)alloc((size_t)8388608*2);
  u16* kb    = (u16*)alloc((size_t)2097152*2);   // B*S x KVD = 4096 x 512
  u16* vtb   = (u16*)alloc((size_t)2097152*2);   // B*G x 64 x S
  u16* ab    = (u16*)alloc((size_t)8388608*2);
  if (ws_size < off) return;

  CvtArgs ca{ x, Wq, Wk, Wv, Wo, xb, wqkvb, wob };
  k_cvt5<<<2048,256,0,stream>>>(ca);

  // fused QKV projection: M=4096, N=3072, epilogue routes per col-range
  k_gemm<3><<<dim3(32,24,1),512,0,stream>>>(xb, wqkvb, qb, kb, vtb, cosp, sinp, 3072, 2048);

  k_fattn<<<dim3(512,1,1),512,0,stream>>>(qb, kb, vtb, ab);

  // output projection -> fp32 d_out
  k_gemm<0><<<dim3(32,16,1),512,0,stream>>>(ab, wob, d_out, nullptr, nullptr, nullptr, nullptr, 2048, 2048);
}